// Round 20
// baseline (224.244 us; speedup 1.0000x reference)
//
#include <hip/hip_runtime.h>
#include <hip/hip_bf16.h>
#include <float.h>

// Performer FastAttention (FAVOR+), MFMA bf16-split v14.
// Round 20: accumulator-chain splitting (dep-latency test).
//  - kside dd: 3 independent MFMA accumulators (chain 6 -> 2), summed after.
//  - qside dd: same 3-way split (both phases).
//  - qside out-GEMM: even/odd-kc accumulator pair (chain 8 -> 4).
// Everything else identical to r19 (best-known 212 µs config).

typedef __attribute__((ext_vector_type(8))) short short8v;
typedef __attribute__((ext_vector_type(4))) short short4v;
typedef __attribute__((ext_vector_type(4))) float f32x4;

#define MFMA32(a, b, c) __builtin_amdgcn_mfma_f32_16x16x32_bf16(a, b, c, 0, 0, 0)

#if defined(__has_builtin)
#if __has_builtin(__builtin_amdgcn_mfma_f32_16x16x16bf16_1k)
#define HAVE_MFMA16_1K 1
#endif
#endif
#ifdef HAVE_MFMA16_1K
#define MFMA16K(a, b, c) __builtin_amdgcn_mfma_f32_16x16x16bf16_1k(a, b, c, 0, 0, 0)
#else
static __device__ __forceinline__ f32x4 mfma16k_asm(short4v a, short4v b, f32x4 c) {
  asm("s_nop 1\n\tv_mfma_f32_16x16x16_bf16 %0, %1, %2, %0" : "+v"(c) : "v"(a), "v"(b));
  return c;
}
#define MFMA16K(a, b, c) mfma16k_asm(a, b, c)
#endif

namespace {
constexpr int Nn = 4096, Dd = 64, BHn = 96;
constexpr float kNorm = 0.35355339059327379f;  // 64^-0.25
constexpr float kDiagCoef = 0.0625f;           // 0.5 * 64^-0.5
constexpr float kEps = 1e-4f;

constexpr size_t oStab  = 0;                                   // 96 u32
constexpr size_t oEsum  = 512;                                 // 96*256 f32
constexpr size_t oVsum  = oEsum + (size_t)BHn * 256 * 4;       // 96*64 f32
constexpr size_t oKshat = oVsum + (size_t)BHn * 64 * 4;        // 96*256 f32
constexpr size_t oCtxE  = oKshat + (size_t)BHn * 256 * 4;      // 96*256*64 f32
constexpr size_t oCtH   = oCtxE + (size_t)BHn * 256 * 64 * 4;  // 96*64*256 bf16
constexpr size_t oPh    = oCtH + (size_t)BHn * 64 * 256 * 2;   // 256*64 bf16
constexpr size_t oPl    = oPh + (size_t)256 * 64 * 2;
constexpr size_t kZeroBytes = oCtH;  // zero stab..ctxE accumulators
}

static __device__ __forceinline__ unsigned floatKey(float f) {
  unsigned b = __float_as_uint(f);
  return (b & 0x80000000u) ? ~b : (b | 0x80000000u);
}
static __device__ __forceinline__ float keyToFloat(unsigned k) {
  unsigned b = (k & 0x80000000u) ? (k & 0x7fffffffu) : ~k;
  return __uint_as_float(b);
}
static __device__ __forceinline__ short f2bf(float x) {
  union { __hip_bfloat16 h; short s; } u;
  u.h = __float2bfloat16(x);
  return u.s;
}
static __device__ __forceinline__ float bf2f(short s) {
  return __uint_as_float(((unsigned)(unsigned short)s) << 16);
}
static __device__ __forceinline__ void splitbf(float x, short& h, short& l) {
  h = f2bf(x);
  l = f2bf(x - bf2f(h));
}
static __device__ __forceinline__ int sw8(int row, int col)  { return col ^ ((row & 7) << 3); }
static __device__ __forceinline__ int sw16(int row, int col) { return col ^ ((row & 15) << 3); }

// ---------------------------------------------------------------------------
// prep: split proj into bf16 hi/lo, linear [m][d] layout in ws.
// ---------------------------------------------------------------------------
__global__ void perf_prep(const float* __restrict__ proj, short* __restrict__ Ph,
                          short* __restrict__ Pl) {
  const int i = (blockIdx.x * 256 + threadIdx.x) * 4;  // 16384 elems
  float4 v = *(const float4*)(proj + i);
  float xs[4] = {v.x, v.y, v.z, v.w};
  short4v h, l;
#pragma unroll
  for (int j = 0; j < 4; ++j) {
    short hh, ll;
    splitbf(xs[j], hh, ll);
    h[j] = hh;
    l[j] = ll;
  }
  *(short4v*)(Ph + i) = h;
  *(short4v*)(Pl + i) = l;
}

// ---------------------------------------------------------------------------
// kside: grid (96, 8), block 512 (8 waves). 512 k-rows/block, 8 subs of 64.
// V single-bf16, ctx GEMM 1-term, dbuf, 1 barrier/sub, T14 prefetch,
// K-frag ping-pong, setprio. dd = 3 independent accumulator chains.
// ---------------------------------------------------------------------------
__global__ __launch_bounds__(512, 2) void perf_kside(
    const float* __restrict__ K, const float* __restrict__ V,
    const short* __restrict__ PhG, const short* __restrict__ PlG,
    unsigned* __restrict__ stabKey, float* __restrict__ EsumG,
    float* __restrict__ VsumG, float* __restrict__ ctxEG) {
  const int t = threadIdx.x, bh = blockIdx.x, chunk = blockIdx.y;
  const int w = t >> 6, l = t & 63;
  const int lhi = l >> 4, llo = l & 15;
  const int koff = lhi * 8;

  __shared__ short Kh[2][64][64], Kl[2][64][64];
  __shared__ short Vh[2][64][64];                  // V^T bf16: [e][n]
  __shared__ float diag[2][64];
  __shared__ float rpartV[8][64];
  __shared__ float wpmax[8];

  short8v prh[2][2], prl[2][2];
#pragma unroll
  for (int mt = 0; mt < 2; ++mt)
#pragma unroll
    for (int kb = 0; kb < 2; ++kb) {
      const int m = w * 32 + mt * 16 + llo;
      prh[mt][kb] = *(const short8v*)(PhG + m * 64 + kb * 32 + koff);
      prl[mt][kb] = *(const short8v*)(PlG + m * 64 + kb * 32 + koff);
    }

  float mx = -FLT_MAX, vsum_r = 0.f;
  f32x4 cacc[2][4];
  float es[2] = {0.f, 0.f};
#pragma unroll
  for (int a = 0; a < 2; ++a)
#pragma unroll
    for (int b = 0; b < 4; ++b) cacc[a][b] = f32x4{0.f, 0.f, 0.f, 0.f};

  const size_t base = ((size_t)bh * Nn + chunk * 512) * Dd;
  const int nK = t >> 3, d0K = (t & 7) * 8;
  const int eV = l, n0V = w * 8;
  const float* Kp = K + base + (size_t)nK * 64 + d0K;
  const float* Vp = V + base + (size_t)n0V * 64 + eV;

  float4 ka, kb4;
  float vv[8];

  auto LOADR = [&](int s) {
    const float* kn = Kp + (size_t)s * 64 * 64;
    const float* vn = Vp + (size_t)s * 64 * 64;
    ka = *(const float4*)kn;
    kb4 = *(const float4*)(kn + 4);
#pragma unroll
    for (int i = 0; i < 8; ++i) vv[i] = vn[i * 64];
  };
  auto WRITE = [&](int bi) {
    {  // K split + diag partial
      float xs[8] = {ka.x, ka.y, ka.z, ka.w, kb4.x, kb4.y, kb4.z, kb4.w};
      float s = 0.f;
#pragma unroll
      for (int i = 0; i < 8; ++i) s = fmaf(xs[i], xs[i], s);
      s += __shfl_xor(s, 1); s += __shfl_xor(s, 2); s += __shfl_xor(s, 4);
      if ((t & 7) == 0) diag[bi][nK] = s * kDiagCoef;
      short8v h8, l8;
#pragma unroll
      for (int i = 0; i < 8; ++i) {
        short hh, ll;
        splitbf(kNorm * xs[i], hh, ll);
        h8[i] = hh; l8[i] = ll;
      }
      const int c = sw8(nK, d0K);
      *(short8v*)&Kh[bi][nK][c] = h8;
      *(short8v*)&Kl[bi][nK][c] = l8;
    }
    {  // V^T single-bf16 (+vsum)
      short8v h8;
#pragma unroll
      for (int i = 0; i < 8; ++i) {
        vsum_r += vv[i];
        h8[i] = f2bf(vv[i]);
      }
      const int c = sw8(eV, n0V);
      *(short8v*)&Vh[bi][eV][c] = h8;
    }
  };

  LOADR(0);
  WRITE(0);
  LOADR(1);
  __syncthreads();

  for (int s = 0; s < 8; ++s) {
    const int cur = s & 1;
    if (s < 7) {
      WRITE(cur ^ 1);
      if (s < 6) LOADR(s + 2);
    }
    __builtin_amdgcn_s_setprio(1);
    short8v kh2[2][2], kl2[2][2];
    {
      const int arow = llo;
#pragma unroll
      for (int kb = 0; kb < 2; ++kb) {
        const int c = sw8(arow, kb * 32 + koff);
        kh2[0][kb] = *(const short8v*)&Kh[cur][arow][c];
        kl2[0][kb] = *(const short8v*)&Kl[cur][arow][c];
      }
    }
#pragma unroll
    for (int b = 0; b < 4; ++b) {
      const int pb = b & 1, nb = pb ^ 1;
      if (b < 3) {
        const int arow = (b + 1) * 16 + llo;
#pragma unroll
        for (int kb = 0; kb < 2; ++kb) {
          const int c = sw8(arow, kb * 32 + koff);
          kh2[nb][kb] = *(const short8v*)&Kh[cur][arow][c];
          kl2[nb][kb] = *(const short8v*)&Kl[cur][arow][c];
        }
      }
      short4v vh[4];
#pragma unroll
      for (int et = 0; et < 4; ++et) {
        const int ecol = et * 16 + llo;
        const int cc = sw8(ecol, b * 16 + lhi * 4);
        vh[et] = *(const short4v*)&Vh[cur][ecol][cc];
      }
      const f32x4 dg = *(const f32x4*)&diag[cur][b * 16 + lhi * 4];

#pragma unroll
      for (int mt = 0; mt < 2; ++mt) {
        // dd: three independent 2-deep chains
        f32x4 a1 = f32x4{0.f, 0.f, 0.f, 0.f};
        f32x4 a2 = f32x4{0.f, 0.f, 0.f, 0.f};
        f32x4 a3 = f32x4{0.f, 0.f, 0.f, 0.f};
#pragma unroll
        for (int kb = 0; kb < 2; ++kb) {
          a1 = MFMA32(kh2[pb][kb], prh[mt][kb], a1);
          a2 = MFMA32(kh2[pb][kb], prl[mt][kb], a2);
          a3 = MFMA32(kl2[pb][kb], prh[mt][kb], a3);
        }
        short4v h4;
        float esa = 0.f;
#pragma unroll
        for (int jj = 0; jj < 4; ++jj) {
          float dd = a1[jj] + a2[jj] + a3[jj];
          mx = fmaxf(mx, dd);
          float E = __expf(dd - dg[jj]);
          short hh = f2bf(E);
          h4[jj] = hh;
          esa += bf2f(hh);
        }
        es[mt] += esa;
#pragma unroll
        for (int et = 0; et < 4; ++et) {
          cacc[mt][et] = MFMA16K(h4, vh[et], cacc[mt][et]);
        }
      }
    }
    __builtin_amdgcn_s_setprio(0);
    __syncthreads();
  }

#pragma unroll
  for (int off = 32; off; off >>= 1) mx = fmaxf(mx, __shfl_xor(mx, off));
  if (l == 0) wpmax[w] = mx;
#pragma unroll
  for (int mt = 0; mt < 2; ++mt) {
    float v2 = es[mt];
    v2 += __shfl_xor(v2, 16);
    v2 += __shfl_xor(v2, 32);
    if (l < 16) atomicAdd(&EsumG[bh * 256 + w * 32 + mt * 16 + l], v2);
  }
  rpartV[w][l] = vsum_r;
  __syncthreads();
  if (t < 64) {
    float s2 = 0.f;
#pragma unroll
    for (int w2 = 0; w2 < 8; ++w2) s2 += rpartV[w2][t];
    atomicAdd(&VsumG[bh * 64 + t], s2);
  }
  if (t == 0) {
    float b = wpmax[0];
#pragma unroll
    for (int w2 = 1; w2 < 8; ++w2) b = fmaxf(b, wpmax[w2]);
    atomicMax(stabKey + bh, floatKey(b));
  }
#pragma unroll
  for (int mt = 0; mt < 2; ++mt)
#pragma unroll
    for (int et = 0; et < 4; ++et)
#pragma unroll
      for (int jj = 0; jj < 4; ++jj) {
        const int m2 = w * 32 + mt * 16 + lhi * 4 + jj;
        const int e2 = et * 16 + llo;
        atomicAdd(&ctxEG[((size_t)bh * 256 + m2) * 64 + e2], cacc[mt][et][jj]);
      }
}

// ---------------------------------------------------------------------------
// combine: grid (96, 4), block 256. Coalesced f4 reads -> LDS tile
// (stride 65) -> transposed short8 writes. ctH only.
// ---------------------------------------------------------------------------
__global__ __launch_bounds__(256) void perf_combine(
    const unsigned* __restrict__ stabKey, const float* __restrict__ EsumG,
    const float* __restrict__ VsumG, const float* __restrict__ ctxEG,
    float* __restrict__ kshatG, short* __restrict__ ctHG) {
  const int bh = blockIdx.x, mblk = blockIdx.y, t = threadIdx.x;
  const int m0 = mblk * 64;
  __shared__ float tile[64][65];
  const float esc = __expf(-keyToFloat(stabKey[bh]));

  {
    const int m = t >> 2, e0 = (t & 3) * 16;
    const float* src = ctxEG + ((size_t)bh * 256 + m0 + m) * 64 + e0;
    float4 a0 = *(const float4*)src;
    float4 a1 = *(const float4*)(src + 4);
    float4 a2 = *(const float4*)(src + 8);
    float4 a3 = *(const float4*)(src + 12);
    float xs[16] = {a0.x, a0.y, a0.z, a0.w, a1.x, a1.y, a1.z, a1.w,
                    a2.x, a2.y, a2.z, a2.w, a3.x, a3.y, a3.z, a3.w};
#pragma unroll
    for (int j = 0; j < 16; ++j) tile[m][e0 + j] = xs[j];
  }
  if (t < 64) kshatG[bh * 256 + m0 + t] = esc * EsumG[bh * 256 + m0 + t] + kEps * 4096.0f;
  __syncthreads();

  {
    const int e = t >> 2, ml0 = (t & 3) * 16;
    const float vadd = kEps * VsumG[bh * 64 + e];
    short8v h0, h1;
#pragma unroll
    for (int j = 0; j < 8; ++j) h0[j] = f2bf(esc * tile[ml0 + j][e] + vadd);
#pragma unroll
    for (int j = 0; j < 8; ++j) h1[j] = f2bf(esc * tile[ml0 + 8 + j][e] + vadd);
    short* dh = ctHG + ((size_t)bh * 64 + e) * 256 + m0 + ml0;
    *(short8v*)dh = h0;
    *(short8v*)(dh + 8) = h1;
  }
}

// ---------------------------------------------------------------------------
// qside: grid (96, 64), block 512. 64 q-rows/block. dd 3-way chain split;
// out GEMM even/odd-kc accumulator pair. ctTh staged with reg prefetch.
// ---------------------------------------------------------------------------
__global__ __launch_bounds__(512, 2) void perf_qside(
    const float* __restrict__ Q, const short* __restrict__ PhG,
    const short* __restrict__ PlG, const float* __restrict__ kshatG,
    const short* __restrict__ ctHG, float* __restrict__ out) {
  const int t = threadIdx.x, bh = blockIdx.x, rb = blockIdx.y;
  const int w = t >> 6, l = t & 63;
  const int rt = w & 3, ms = w >> 2;
  const int lhi = l >> 4, llo = l & 15;
  const int koff = lhi * 8;

  __shared__ short Ph[128][64], Pl[128][64];  // per-phase proj; Ph reused as ctTh[64][128]
  __shared__ short qph[64][256];              // q' bf16 (hi only)
  __shared__ float kshatL[256];
  __shared__ unsigned rmaxKey[64];
  __shared__ float denL[64];

  const int iP = t >> 2, d0P = (t & 3) * 16;          // proj staging
  const int eC = t >> 3, mgC = t & 7;                 // ctTh staging

  short8v p0a = *(const short8v*)(PhG + iP * 64 + d0P);
  short8v p0b = *(const short8v*)(PhG + iP * 64 + d0P + 8);
  short8v p0c = *(const short8v*)(PlG + iP * 64 + d0P);
  short8v p0d = *(const short8v*)(PlG + iP * 64 + d0P + 8);

  if (t < 64) { rmaxKey[t] = 0u; denL[t] = 0.f; }
  if (t < 256) kshatL[t] = kshatG[bh * 256 + t];

  const int r = rt * 16 + llo;

  short8v qh[2], ql[2];
  float dgq;
  {
    const float* qs = Q + ((size_t)bh * Nn + rb * 64 + r) * 64 + koff;
    float4 a0 = *(const float4*)qs;
    float4 a1 = *(const float4*)(qs + 4);
    float4 b0 = *(const float4*)(qs + 32);
    float4 b1 = *(const float4*)(qs + 36);
    float xs[16] = {a0.x, a0.y, a0.z, a0.w, a1.x, a1.y, a1.z, a1.w,
                    b0.x, b0.y, b0.z, b0.w, b1.x, b1.y, b1.z, b1.w};
    float s = 0.f;
#pragma unroll
    for (int i = 0; i < 16; ++i) s = fmaf(xs[i], xs[i], s);
    s += __shfl_xor(s, 16);
    s += __shfl_xor(s, 32);
    dgq = s * kDiagCoef;
#pragma unroll
    for (int kb = 0; kb < 2; ++kb) {
      short8v h8, l8;
#pragma unroll
      for (int i = 0; i < 8; ++i) {
        short hh, ll;
        splitbf(kNorm * xs[kb * 8 + i], hh, ll);
        h8[i] = hh; l8[i] = ll;
      }
      qh[kb] = h8; ql[kb] = l8;
    }
  }
  __syncthreads();  // init visible

  {
    const int c0 = sw8(iP, d0P), c1 = sw8(iP, d0P + 8);
    *(short8v*)&Ph[iP][c0] = p0a;
    *(short8v*)&Ph[iP][c1] = p0b;
    *(short8v*)&Pl[iP][c0] = p0c;
    *(short8v*)&Pl[iP][c1] = p0d;
  }
  p0a = *(const short8v*)(PhG + (128 + iP) * 64 + d0P);
  p0b = *(const short8v*)(PhG + (128 + iP) * 64 + d0P + 8);
  p0c = *(const short8v*)(PlG + (128 + iP) * 64 + d0P);
  p0d = *(const short8v*)(PlG + (128 + iP) * 64 + d0P + 8);
  __syncthreads();

  f32x4 dacc[8];
#pragma unroll
  for (int mt = 0; mt < 4; ++mt) {  // dd ph0 (proj h1 loads in flight)
    const int mrow = ms * 64 + mt * 16 + llo;
    f32x4 a1 = f32x4{0.f, 0.f, 0.f, 0.f};
    f32x4 a2 = f32x4{0.f, 0.f, 0.f, 0.f};
    f32x4 a3 = f32x4{0.f, 0.f, 0.f, 0.f};
#pragma unroll
    for (int kb = 0; kb < 2; ++kb) {
      const int c = sw8(mrow, kb * 32 + koff);
      short8v pbh = *(const short8v*)&Ph[mrow][c];
      short8v pbl = *(const short8v*)&Pl[mrow][c];
      a1 = MFMA32(pbh, qh[kb], a1);
      a2 = MFMA32(pbh, ql[kb], a2);
      a3 = MFMA32(pbl, qh[kb], a3);
    }
    dacc[mt] = a1 + a2 + a3;
  }
  __syncthreads();  // ph0 dd reads done

  {
    const int c0 = sw8(iP, d0P), c1 = sw8(iP, d0P + 8);
    *(short8v*)&Ph[iP][c0] = p0a;
    *(short8v*)&Ph[iP][c1] = p0b;
    *(short8v*)&Pl[iP][c0] = p0c;
    *(short8v*)&Pl[iP][c1] = p0d;
  }
  {  // issue ctTh h0 loads
    const short* gh = ctHG + ((size_t)bh * 64 + eC) * 256 + mgC * 16;
    p0a = *(const short8v*)gh;
    p0b = *(const short8v*)(gh + 8);
  }
  __syncthreads();

#pragma unroll
  for (int mt = 0; mt < 4; ++mt) {  // dd ph1 (ctTh h0 loads in flight)
    const int mrow = ms * 64 + mt * 16 + llo;
    f32x4 a1 = f32x4{0.f, 0.f, 0.f, 0.f};
    f32x4 a2 = f32x4{0.f, 0.f, 0.f, 0.f};
    f32x4 a3 = f32x4{0.f, 0.f, 0.f, 0.f};
#pragma unroll
    for (int kb = 0; kb < 2; ++kb) {
      const int c = sw8(mrow, kb * 32 + koff);
      short8v pbh = *(const short8v*)&Ph[mrow][c];
      short8v pbl = *(const short8v*)&Pl[mrow][c];
      a1 = MFMA32(pbh, qh[kb], a1);
      a2 = MFMA32(pbh, ql[kb], a2);
      a3 = MFMA32(pbl, qh[kb], a3);
    }
    dacc[4 + mt] = a1 + a2 + a3;
  }

  {
    float mx = dacc[0][0];
#pragma unroll
    for (int i = 0; i < 8; ++i)
#pragma unroll
      for (int jj = 0; jj < 4; ++jj) mx = fmaxf(mx, dacc[i][jj]);
    mx = fmaxf(mx, __shfl_xor(mx, 16));
    mx = fmaxf(mx, __shfl_xor(mx, 32));
    if (l < 16) atomicMax(&rmaxKey[rt * 16 + l], floatKey(mx));
  }
  __syncthreads();

  {
    const float shift = dgq + keyToFloat(rmaxKey[r]);
    float den = 0.f;
#pragma unroll
    for (int i = 0; i < 8; ++i) {
      const int m0 = (i >> 2) * 128 + ms * 64 + (i & 3) * 16 + lhi * 4;
      const f32x4 ksv = *(const f32x4*)&kshatL[m0];
      short4v h4;
#pragma unroll
      for (int jj = 0; jj < 4; ++jj) {
        float qv = __expf(dacc[i][jj] - shift) + kEps;
        short hh = f2bf(qv);
        h4[jj] = hh;
        den = fmaf(bf2f(hh), ksv[jj], den);
      }
      const int c = m0 ^ ((r & 31) << 3);
      *(short4v*)&qph[r][c] = h4;
    }
    den += __shfl_xor(den, 16);
    den += __shfl_xor(den, 32);
    if (l < 16) atomicAdd(&denL[rt * 16 + l], den);
  }
  __syncthreads();  // qph/den visible; Ph/Pl dd reads done

  short(*ctTh)[128] = (short(*)[128])Ph;
  f32x4 oaccA[2] = {f32x4{0.f, 0.f, 0.f, 0.f}, f32x4{0.f, 0.f, 0.f, 0.f}};
  f32x4 oaccB[2] = {f32x4{0.f, 0.f, 0.f, 0.f}, f32x4{0.f, 0.f, 0.f, 0.f}};

  // write ctTh h0; issue ctTh h1 loads
  {
    *(short8v*)&ctTh[eC][sw16(eC, mgC * 16)] = p0a;
    *(short8v*)&ctTh[eC][sw16(eC, mgC * 16 + 8)] = p0b;
  }
  {
    const short* gh = ctHG + ((size_t)bh * 64 + eC) * 256 + 128 + mgC * 16;
    p0a = *(const short8v*)gh;
    p0b = *(const short8v*)(gh + 8);
  }
  __syncthreads();

#pragma unroll
  for (int mh2 = 0; mh2 < 2; ++mh2) {
    if (mh2 == 1) {
      __syncthreads();  // out GEMM h0 reads done
      *(short8v*)&ctTh[eC][sw16(eC, mgC * 16)] = p0a;
      *(short8v*)&ctTh[eC][sw16(eC, mgC * 16 + 8)] = p0b;
      __syncthreads();
    }
    // kc pairs: even kc -> oaccA, odd kc -> oaccB (4-deep chains each)
#pragma unroll
    for (int kc2 = 0; kc2 < 2; ++kc2) {
      const int kcA = kc2 * 2, kcB = kc2 * 2 + 1;
      const int mbA = mh2 * 128 + kcA * 32 + koff;
      const int mbB = mh2 * 128 + kcB * 32 + koff;
      short8v qA = *(const short8v*)&qph[r][mbA ^ ((r & 31) << 3)];
      short8v qB = *(const short8v*)&qph[r][mbB ^ ((r & 31) << 3)];
#pragma unroll
      for (int et = 0; et < 2; ++et) {
        const int erow = (ms * 2 + et) * 16 + llo;
        short8v thA = *(const short8v*)&ctTh[erow][sw16(erow, kcA * 32 + koff)];
        short8v thB = *(const short8v*)&ctTh[erow][sw16(erow, kcB * 32 + koff)];
        oaccA[et] = MFMA32(qA, thA, oaccA[et]);
        oaccB[et] = MFMA32(qB, thB, oaccB[et]);
      }
    }
  }

  float inv[4];
#pragma unroll
  for (int jj = 0; jj < 4; ++jj) inv[jj] = 1.0f / denL[rt * 16 + lhi * 4 + jj];
#pragma unroll
  for (int et = 0; et < 2; ++et)
#pragma unroll
    for (int jj = 0; jj < 4; ++jj) {
      const int ro = rt * 16 + lhi * 4 + jj;
      const int e2 = (ms * 2 + et) * 16 + llo;
      out[((size_t)bh * Nn + rb * 64 + ro) * 64 + e2] =
          (oaccA[et][jj] + oaccB[et][jj]) * inv[jj];
    }
}

extern "C" void kernel_launch(void* const* d_in, const int* in_sizes, int n_in,
                              void* d_out, int out_size, void* d_ws, size_t ws_size,
                              hipStream_t stream) {
  const float* q = (const float*)d_in[0];
  const float* k = (const float*)d_in[1];
  const float* v = (const float*)d_in[2];
  const float* proj = (const float*)d_in[3];
  float* outp = (float*)d_out;

  char* ws = (char*)d_ws;
  unsigned* stabKey = (unsigned*)(ws + oStab);
  float* EsumG = (float*)(ws + oEsum);
  float* VsumG = (float*)(ws + oVsum);
  float* kshatG = (float*)(ws + oKshat);
  float* ctxEG = (float*)(ws + oCtxE);
  short* ctHG = (short*)(ws + oCtH);
  short* PhG = (short*)(ws + oPh);
  short* PlG = (short*)(ws + oPl);

  hipMemsetAsync(d_ws, 0, kZeroBytes, stream);
  perf_prep<<<16, 256, 0, stream>>>(proj, PhG, PlG);
  perf_kside<<<dim3(BHn, 8), 512, 0, stream>>>(k, v, PhG, PlG, stabKey, EsumG, VsumG, ctxEG);
  perf_combine<<<dim3(BHn, 4), 256, 0, stream>>>(stabKey, EsumG, VsumG, ctxEG, kshatG, ctHG);
  perf_qside<<<dim3(BHn, 64), 512, 0, stream>>>(q, PhG, PlG, kshatG, ctHG, outp);
}

// Round 21
// 207.127 us; speedup vs baseline: 1.0826x; 1.0826x over previous
//
#include <hip/hip_runtime.h>
#include <hip/hip_bf16.h>
#include <float.h>

// Performer FastAttention (FAVOR+), MFMA bf16-split — FINAL (r19 config).
// Best-known: 212.6 µs, absmax 9.77e-4 (threshold 3.34e-3).
// kside (96,8): V single-bf16, ctx GEMM 1-term via 16x16x16 MFMA from regs,
//   LDS dbuf 1-barrier/sub, T14 reg prefetch, K-frag ping-pong, setprio.
// combine (96,4): coalesced LDS-transpose, ctH only.
// qside (96,64): proj per-half + prefetch, lane-local rowmax/den, q' bf16-hi
//   with den from same rounded weights, out GEMM 1-term, ctTh reg-prefetch.
// r20's chain-splitting regressed qside (regalloc -> 52 VGPR); reverted.

typedef __attribute__((ext_vector_type(8))) short short8v;
typedef __attribute__((ext_vector_type(4))) short short4v;
typedef __attribute__((ext_vector_type(4))) float f32x4;

#define MFMA32(a, b, c) __builtin_amdgcn_mfma_f32_16x16x32_bf16(a, b, c, 0, 0, 0)

#if defined(__has_builtin)
#if __has_builtin(__builtin_amdgcn_mfma_f32_16x16x16bf16_1k)
#define HAVE_MFMA16_1K 1
#endif
#endif
#ifdef HAVE_MFMA16_1K
#define MFMA16K(a, b, c) __builtin_amdgcn_mfma_f32_16x16x16bf16_1k(a, b, c, 0, 0, 0)
#else
static __device__ __forceinline__ f32x4 mfma16k_asm(short4v a, short4v b, f32x4 c) {
  asm("s_nop 1\n\tv_mfma_f32_16x16x16_bf16 %0, %1, %2, %0" : "+v"(c) : "v"(a), "v"(b));
  return c;
}
#define MFMA16K(a, b, c) mfma16k_asm(a, b, c)
#endif

namespace {
constexpr int Nn = 4096, Dd = 64, BHn = 96;
constexpr float kNorm = 0.35355339059327379f;  // 64^-0.25
constexpr float kDiagCoef = 0.0625f;           // 0.5 * 64^-0.5
constexpr float kEps = 1e-4f;

constexpr size_t oStab  = 0;                                   // 96 u32
constexpr size_t oEsum  = 512;                                 // 96*256 f32
constexpr size_t oVsum  = oEsum + (size_t)BHn * 256 * 4;       // 96*64 f32
constexpr size_t oKshat = oVsum + (size_t)BHn * 64 * 4;        // 96*256 f32
constexpr size_t oCtxE  = oKshat + (size_t)BHn * 256 * 4;      // 96*256*64 f32
constexpr size_t oCtH   = oCtxE + (size_t)BHn * 256 * 64 * 4;  // 96*64*256 bf16
constexpr size_t oPh    = oCtH + (size_t)BHn * 64 * 256 * 2;   // 256*64 bf16
constexpr size_t oPl    = oPh + (size_t)256 * 64 * 2;
constexpr size_t kZeroBytes = oCtH;  // zero stab..ctxE accumulators
}

static __device__ __forceinline__ unsigned floatKey(float f) {
  unsigned b = __float_as_uint(f);
  return (b & 0x80000000u) ? ~b : (b | 0x80000000u);
}
static __device__ __forceinline__ float keyToFloat(unsigned k) {
  unsigned b = (k & 0x80000000u) ? (k & 0x7fffffffu) : ~k;
  return __uint_as_float(b);
}
static __device__ __forceinline__ short f2bf(float x) {
  union { __hip_bfloat16 h; short s; } u;
  u.h = __float2bfloat16(x);
  return u.s;
}
static __device__ __forceinline__ float bf2f(short s) {
  return __uint_as_float(((unsigned)(unsigned short)s) << 16);
}
static __device__ __forceinline__ void splitbf(float x, short& h, short& l) {
  h = f2bf(x);
  l = f2bf(x - bf2f(h));
}
static __device__ __forceinline__ int sw8(int row, int col)  { return col ^ ((row & 7) << 3); }
static __device__ __forceinline__ int sw16(int row, int col) { return col ^ ((row & 15) << 3); }

// ---------------------------------------------------------------------------
// prep: split proj into bf16 hi/lo, linear [m][d] layout in ws.
// ---------------------------------------------------------------------------
__global__ void perf_prep(const float* __restrict__ proj, short* __restrict__ Ph,
                          short* __restrict__ Pl) {
  const int i = (blockIdx.x * 256 + threadIdx.x) * 4;  // 16384 elems
  float4 v = *(const float4*)(proj + i);
  float xs[4] = {v.x, v.y, v.z, v.w};
  short4v h, l;
#pragma unroll
  for (int j = 0; j < 4; ++j) {
    short hh, ll;
    splitbf(xs[j], hh, ll);
    h[j] = hh;
    l[j] = ll;
  }
  *(short4v*)(Ph + i) = h;
  *(short4v*)(Pl + i) = l;
}

// ---------------------------------------------------------------------------
// kside: grid (96, 8), block 512 (8 waves). 512 k-rows/block, 8 subs of 64.
// ---------------------------------------------------------------------------
__global__ __launch_bounds__(512, 2) void perf_kside(
    const float* __restrict__ K, const float* __restrict__ V,
    const short* __restrict__ PhG, const short* __restrict__ PlG,
    unsigned* __restrict__ stabKey, float* __restrict__ EsumG,
    float* __restrict__ VsumG, float* __restrict__ ctxEG) {
  const int t = threadIdx.x, bh = blockIdx.x, chunk = blockIdx.y;
  const int w = t >> 6, l = t & 63;
  const int lhi = l >> 4, llo = l & 15;
  const int koff = lhi * 8;

  __shared__ short Kh[2][64][64], Kl[2][64][64];
  __shared__ short Vh[2][64][64];                  // V^T bf16: [e][n]
  __shared__ float diag[2][64];
  __shared__ float rpartV[8][64];
  __shared__ float wpmax[8];

  short8v prh[2][2], prl[2][2];
#pragma unroll
  for (int mt = 0; mt < 2; ++mt)
#pragma unroll
    for (int kb = 0; kb < 2; ++kb) {
      const int m = w * 32 + mt * 16 + llo;
      prh[mt][kb] = *(const short8v*)(PhG + m * 64 + kb * 32 + koff);
      prl[mt][kb] = *(const short8v*)(PlG + m * 64 + kb * 32 + koff);
    }

  float mx = -FLT_MAX, vsum_r = 0.f;
  f32x4 cacc[2][4];
  float es[2] = {0.f, 0.f};
#pragma unroll
  for (int a = 0; a < 2; ++a)
#pragma unroll
    for (int b = 0; b < 4; ++b) cacc[a][b] = f32x4{0.f, 0.f, 0.f, 0.f};

  const size_t base = ((size_t)bh * Nn + chunk * 512) * Dd;
  const int nK = t >> 3, d0K = (t & 7) * 8;
  const int eV = l, n0V = w * 8;
  const float* Kp = K + base + (size_t)nK * 64 + d0K;
  const float* Vp = V + base + (size_t)n0V * 64 + eV;

  float4 ka, kb4;
  float vv[8];

  auto LOADR = [&](int s) {
    const float* kn = Kp + (size_t)s * 64 * 64;
    const float* vn = Vp + (size_t)s * 64 * 64;
    ka = *(const float4*)kn;
    kb4 = *(const float4*)(kn + 4);
#pragma unroll
    for (int i = 0; i < 8; ++i) vv[i] = vn[i * 64];
  };
  auto WRITE = [&](int bi) {
    {  // K split + diag partial
      float xs[8] = {ka.x, ka.y, ka.z, ka.w, kb4.x, kb4.y, kb4.z, kb4.w};
      float s = 0.f;
#pragma unroll
      for (int i = 0; i < 8; ++i) s = fmaf(xs[i], xs[i], s);
      s += __shfl_xor(s, 1); s += __shfl_xor(s, 2); s += __shfl_xor(s, 4);
      if ((t & 7) == 0) diag[bi][nK] = s * kDiagCoef;
      short8v h8, l8;
#pragma unroll
      for (int i = 0; i < 8; ++i) {
        short hh, ll;
        splitbf(kNorm * xs[i], hh, ll);
        h8[i] = hh; l8[i] = ll;
      }
      const int c = sw8(nK, d0K);
      *(short8v*)&Kh[bi][nK][c] = h8;
      *(short8v*)&Kl[bi][nK][c] = l8;
    }
    {  // V^T single-bf16 (+vsum)
      short8v h8;
#pragma unroll
      for (int i = 0; i < 8; ++i) {
        vsum_r += vv[i];
        h8[i] = f2bf(vv[i]);
      }
      const int c = sw8(eV, n0V);
      *(short8v*)&Vh[bi][eV][c] = h8;
    }
  };

  LOADR(0);
  WRITE(0);
  LOADR(1);
  __syncthreads();

  for (int s = 0; s < 8; ++s) {
    const int cur = s & 1;
    if (s < 7) {
      WRITE(cur ^ 1);
      if (s < 6) LOADR(s + 2);
    }
    __builtin_amdgcn_s_setprio(1);
    short8v kh2[2][2], kl2[2][2];
    {
      const int arow = llo;
#pragma unroll
      for (int kb = 0; kb < 2; ++kb) {
        const int c = sw8(arow, kb * 32 + koff);
        kh2[0][kb] = *(const short8v*)&Kh[cur][arow][c];
        kl2[0][kb] = *(const short8v*)&Kl[cur][arow][c];
      }
    }
#pragma unroll
    for (int b = 0; b < 4; ++b) {
      const int pb = b & 1, nb = pb ^ 1;
      if (b < 3) {
        const int arow = (b + 1) * 16 + llo;
#pragma unroll
        for (int kb = 0; kb < 2; ++kb) {
          const int c = sw8(arow, kb * 32 + koff);
          kh2[nb][kb] = *(const short8v*)&Kh[cur][arow][c];
          kl2[nb][kb] = *(const short8v*)&Kl[cur][arow][c];
        }
      }
      short4v vh[4];
#pragma unroll
      for (int et = 0; et < 4; ++et) {
        const int ecol = et * 16 + llo;
        const int cc = sw8(ecol, b * 16 + lhi * 4);
        vh[et] = *(const short4v*)&Vh[cur][ecol][cc];
      }
      const f32x4 dg = *(const f32x4*)&diag[cur][b * 16 + lhi * 4];

#pragma unroll
      for (int mt = 0; mt < 2; ++mt) {
        f32x4 acc = f32x4{0.f, 0.f, 0.f, 0.f};
#pragma unroll
        for (int kb = 0; kb < 2; ++kb) {
          acc = MFMA32(kh2[pb][kb], prh[mt][kb], acc);
          acc = MFMA32(kh2[pb][kb], prl[mt][kb], acc);
          acc = MFMA32(kl2[pb][kb], prh[mt][kb], acc);
        }
        short4v h4;
        float esa = 0.f;
#pragma unroll
        for (int jj = 0; jj < 4; ++jj) {
          float dd = acc[jj];
          mx = fmaxf(mx, dd);
          float E = __expf(dd - dg[jj]);
          short hh = f2bf(E);
          h4[jj] = hh;
          esa += bf2f(hh);
        }
        es[mt] += esa;
#pragma unroll
        for (int et = 0; et < 4; ++et) {
          cacc[mt][et] = MFMA16K(h4, vh[et], cacc[mt][et]);
        }
      }
    }
    __builtin_amdgcn_s_setprio(0);
    __syncthreads();
  }

#pragma unroll
  for (int off = 32; off; off >>= 1) mx = fmaxf(mx, __shfl_xor(mx, off));
  if (l == 0) wpmax[w] = mx;
#pragma unroll
  for (int mt = 0; mt < 2; ++mt) {
    float v2 = es[mt];
    v2 += __shfl_xor(v2, 16);
    v2 += __shfl_xor(v2, 32);
    if (l < 16) atomicAdd(&EsumG[bh * 256 + w * 32 + mt * 16 + l], v2);
  }
  rpartV[w][l] = vsum_r;
  __syncthreads();
  if (t < 64) {
    float s2 = 0.f;
#pragma unroll
    for (int w2 = 0; w2 < 8; ++w2) s2 += rpartV[w2][t];
    atomicAdd(&VsumG[bh * 64 + t], s2);
  }
  if (t == 0) {
    float b = wpmax[0];
#pragma unroll
    for (int w2 = 1; w2 < 8; ++w2) b = fmaxf(b, wpmax[w2]);
    atomicMax(stabKey + bh, floatKey(b));
  }
#pragma unroll
  for (int mt = 0; mt < 2; ++mt)
#pragma unroll
    for (int et = 0; et < 4; ++et)
#pragma unroll
      for (int jj = 0; jj < 4; ++jj) {
        const int m2 = w * 32 + mt * 16 + lhi * 4 + jj;
        const int e2 = et * 16 + llo;
        atomicAdd(&ctxEG[((size_t)bh * 256 + m2) * 64 + e2], cacc[mt][et][jj]);
      }
}

// ---------------------------------------------------------------------------
// combine: grid (96, 4), block 256. Coalesced f4 reads -> LDS tile
// (stride 65) -> transposed short8 writes. ctH only.
// ---------------------------------------------------------------------------
__global__ __launch_bounds__(256) void perf_combine(
    const unsigned* __restrict__ stabKey, const float* __restrict__ EsumG,
    const float* __restrict__ VsumG, const float* __restrict__ ctxEG,
    float* __restrict__ kshatG, short* __restrict__ ctHG) {
  const int bh = blockIdx.x, mblk = blockIdx.y, t = threadIdx.x;
  const int m0 = mblk * 64;
  __shared__ float tile[64][65];
  const float esc = __expf(-keyToFloat(stabKey[bh]));

  {
    const int m = t >> 2, e0 = (t & 3) * 16;
    const float* src = ctxEG + ((size_t)bh * 256 + m0 + m) * 64 + e0;
    float4 a0 = *(const float4*)src;
    float4 a1 = *(const float4*)(src + 4);
    float4 a2 = *(const float4*)(src + 8);
    float4 a3 = *(const float4*)(src + 12);
    float xs[16] = {a0.x, a0.y, a0.z, a0.w, a1.x, a1.y, a1.z, a1.w,
                    a2.x, a2.y, a2.z, a2.w, a3.x, a3.y, a3.z, a3.w};
#pragma unroll
    for (int j = 0; j < 16; ++j) tile[m][e0 + j] = xs[j];
  }
  if (t < 64) kshatG[bh * 256 + m0 + t] = esc * EsumG[bh * 256 + m0 + t] + kEps * 4096.0f;
  __syncthreads();

  {
    const int e = t >> 2, ml0 = (t & 3) * 16;
    const float vadd = kEps * VsumG[bh * 64 + e];
    short8v h0, h1;
#pragma unroll
    for (int j = 0; j < 8; ++j) h0[j] = f2bf(esc * tile[ml0 + j][e] + vadd);
#pragma unroll
    for (int j = 0; j < 8; ++j) h1[j] = f2bf(esc * tile[ml0 + 8 + j][e] + vadd);
    short* dh = ctHG + ((size_t)bh * 64 + e) * 256 + m0 + ml0;
    *(short8v*)dh = h0;
    *(short8v*)(dh + 8) = h1;
  }
}

// ---------------------------------------------------------------------------
// qside: grid (96, 64), block 512. 64 q-rows/block. out GEMM 1-term (ct_h),
// ctTh staged per m-half with reg prefetch; proj per-half with prefetch.
// ---------------------------------------------------------------------------
__global__ __launch_bounds__(512, 2) void perf_qside(
    const float* __restrict__ Q, const short* __restrict__ PhG,
    const short* __restrict__ PlG, const float* __restrict__ kshatG,
    const short* __restrict__ ctHG, float* __restrict__ out) {
  const int t = threadIdx.x, bh = blockIdx.x, rb = blockIdx.y;
  const int w = t >> 6, l = t & 63;
  const int rt = w & 3, ms = w >> 2;
  const int lhi = l >> 4, llo = l & 15;
  const int koff = lhi * 8;

  __shared__ short Ph[128][64], Pl[128][64];  // per-phase proj; Ph reused as ctTh[64][128]
  __shared__ short qph[64][256];              // q' bf16 (hi only)
  __shared__ float kshatL[256];
  __shared__ unsigned rmaxKey[64];
  __shared__ float denL[64];

  const int iP = t >> 2, d0P = (t & 3) * 16;          // proj staging
  const int eC = t >> 3, mgC = t & 7;                 // ctTh staging

  short8v p0a = *(const short8v*)(PhG + iP * 64 + d0P);
  short8v p0b = *(const short8v*)(PhG + iP * 64 + d0P + 8);
  short8v p0c = *(const short8v*)(PlG + iP * 64 + d0P);
  short8v p0d = *(const short8v*)(PlG + iP * 64 + d0P + 8);

  if (t < 64) { rmaxKey[t] = 0u; denL[t] = 0.f; }
  if (t < 256) kshatL[t] = kshatG[bh * 256 + t];

  const int r = rt * 16 + llo;

  short8v qh[2], ql[2];
  float dgq;
  {
    const float* qs = Q + ((size_t)bh * Nn + rb * 64 + r) * 64 + koff;
    float4 a0 = *(const float4*)qs;
    float4 a1 = *(const float4*)(qs + 4);
    float4 b0 = *(const float4*)(qs + 32);
    float4 b1 = *(const float4*)(qs + 36);
    float xs[16] = {a0.x, a0.y, a0.z, a0.w, a1.x, a1.y, a1.z, a1.w,
                    b0.x, b0.y, b0.z, b0.w, b1.x, b1.y, b1.z, b1.w};
    float s = 0.f;
#pragma unroll
    for (int i = 0; i < 16; ++i) s = fmaf(xs[i], xs[i], s);
    s += __shfl_xor(s, 16);
    s += __shfl_xor(s, 32);
    dgq = s * kDiagCoef;
#pragma unroll
    for (int kb = 0; kb < 2; ++kb) {
      short8v h8, l8;
#pragma unroll
      for (int i = 0; i < 8; ++i) {
        short hh, ll;
        splitbf(kNorm * xs[kb * 8 + i], hh, ll);
        h8[i] = hh; l8[i] = ll;
      }
      qh[kb] = h8; ql[kb] = l8;
    }
  }
  __syncthreads();  // init visible

  {
    const int c0 = sw8(iP, d0P), c1 = sw8(iP, d0P + 8);
    *(short8v*)&Ph[iP][c0] = p0a;
    *(short8v*)&Ph[iP][c1] = p0b;
    *(short8v*)&Pl[iP][c0] = p0c;
    *(short8v*)&Pl[iP][c1] = p0d;
  }
  p0a = *(const short8v*)(PhG + (128 + iP) * 64 + d0P);
  p0b = *(const short8v*)(PhG + (128 + iP) * 64 + d0P + 8);
  p0c = *(const short8v*)(PlG + (128 + iP) * 64 + d0P);
  p0d = *(const short8v*)(PlG + (128 + iP) * 64 + d0P + 8);
  __syncthreads();

  f32x4 dacc[8];
#pragma unroll
  for (int mt = 0; mt < 4; ++mt) {  // dd ph0 (proj h1 loads in flight)
    const int mrow = ms * 64 + mt * 16 + llo;
    f32x4 acc = f32x4{0.f, 0.f, 0.f, 0.f};
#pragma unroll
    for (int kb = 0; kb < 2; ++kb) {
      const int c = sw8(mrow, kb * 32 + koff);
      short8v pbh = *(const short8v*)&Ph[mrow][c];
      short8v pbl = *(const short8v*)&Pl[mrow][c];
      acc = MFMA32(pbh, qh[kb], acc);
      acc = MFMA32(pbh, ql[kb], acc);
      acc = MFMA32(pbl, qh[kb], acc);
    }
    dacc[mt] = acc;
  }
  __syncthreads();  // ph0 dd reads done

  {
    const int c0 = sw8(iP, d0P), c1 = sw8(iP, d0P + 8);
    *(short8v*)&Ph[iP][c0] = p0a;
    *(short8v*)&Ph[iP][c1] = p0b;
    *(short8v*)&Pl[iP][c0] = p0c;
    *(short8v*)&Pl[iP][c1] = p0d;
  }
  {  // issue ctTh h0 loads
    const short* gh = ctHG + ((size_t)bh * 64 + eC) * 256 + mgC * 16;
    p0a = *(const short8v*)gh;
    p0b = *(const short8v*)(gh + 8);
  }
  __syncthreads();

#pragma unroll
  for (int mt = 0; mt < 4; ++mt) {  // dd ph1 (ctTh h0 loads in flight)
    const int mrow = ms * 64 + mt * 16 + llo;
    f32x4 acc = f32x4{0.f, 0.f, 0.f, 0.f};
#pragma unroll
    for (int kb = 0; kb < 2; ++kb) {
      const int c = sw8(mrow, kb * 32 + koff);
      short8v pbh = *(const short8v*)&Ph[mrow][c];
      short8v pbl = *(const short8v*)&Pl[mrow][c];
      acc = MFMA32(pbh, qh[kb], acc);
      acc = MFMA32(pbh, ql[kb], acc);
      acc = MFMA32(pbl, qh[kb], acc);
    }
    dacc[4 + mt] = acc;
  }

  {
    float mx = dacc[0][0];
#pragma unroll
    for (int i = 0; i < 8; ++i)
#pragma unroll
      for (int jj = 0; jj < 4; ++jj) mx = fmaxf(mx, dacc[i][jj]);
    mx = fmaxf(mx, __shfl_xor(mx, 16));
    mx = fmaxf(mx, __shfl_xor(mx, 32));
    if (l < 16) atomicMax(&rmaxKey[rt * 16 + l], floatKey(mx));
  }
  __syncthreads();

  {
    const float shift = dgq + keyToFloat(rmaxKey[r]);
    float den = 0.f;
#pragma unroll
    for (int i = 0; i < 8; ++i) {
      const int m0 = (i >> 2) * 128 + ms * 64 + (i & 3) * 16 + lhi * 4;
      const f32x4 ksv = *(const f32x4*)&kshatL[m0];
      short4v h4;
#pragma unroll
      for (int jj = 0; jj < 4; ++jj) {
        float qv = __expf(dacc[i][jj] - shift) + kEps;
        short hh = f2bf(qv);
        h4[jj] = hh;
        den = fmaf(bf2f(hh), ksv[jj], den);
      }
      const int c = m0 ^ ((r & 31) << 3);
      *(short4v*)&qph[r][c] = h4;
    }
    den += __shfl_xor(den, 16);
    den += __shfl_xor(den, 32);
    if (l < 16) atomicAdd(&denL[rt * 16 + l], den);
  }
  __syncthreads();  // qph/den visible; Ph/Pl dd reads done

  short(*ctTh)[128] = (short(*)[128])Ph;
  f32x4 oacc[2] = {f32x4{0.f, 0.f, 0.f, 0.f}, f32x4{0.f, 0.f, 0.f, 0.f}};

  // write ctTh h0; issue ctTh h1 loads
  {
    *(short8v*)&ctTh[eC][sw16(eC, mgC * 16)] = p0a;
    *(short8v*)&ctTh[eC][sw16(eC, mgC * 16 + 8)] = p0b;
  }
  {
    const short* gh = ctHG + ((size_t)bh * 64 + eC) * 256 + 128 + mgC * 16;
    p0a = *(const short8v*)gh;
    p0b = *(const short8v*)(gh + 8);
  }
  __syncthreads();

#pragma unroll
  for (int mh2 = 0; mh2 < 2; ++mh2) {
    if (mh2 == 1) {
      __syncthreads();  // out GEMM h0 reads done
      *(short8v*)&ctTh[eC][sw16(eC, mgC * 16)] = p0a;
      *(short8v*)&ctTh[eC][sw16(eC, mgC * 16 + 8)] = p0b;
      __syncthreads();
    }
#pragma unroll
    for (int kc = 0; kc < 4; ++kc) {
      const int mb = mh2 * 128 + kc * 32 + koff;
      const int ca = mb ^ ((r & 31) << 3);
      short8v qh8 = *(const short8v*)&qph[r][ca];
#pragma unroll
      for (int et = 0; et < 2; ++et) {
        const int erow = (ms * 2 + et) * 16 + llo;
        const int cb = sw16(erow, kc * 32 + koff);
        short8v th = *(const short8v*)&ctTh[erow][cb];
        oacc[et] = MFMA32(qh8, th, oacc[et]);
      }
    }
  }

  float inv[4];
#pragma unroll
  for (int jj = 0; jj < 4; ++jj) inv[jj] = 1.0f / denL[rt * 16 + lhi * 4 + jj];
#pragma unroll
  for (int et = 0; et < 2; ++et)
#pragma unroll
    for (int jj = 0; jj < 4; ++jj) {
      const int ro = rt * 16 + lhi * 4 + jj;
      const int e2 = (ms * 2 + et) * 16 + llo;
      out[((size_t)bh * Nn + rb * 64 + ro) * 64 + e2] = oacc[et][jj] * inv[jj];
    }
}

extern "C" void kernel_launch(void* const* d_in, const int* in_sizes, int n_in,
                              void* d_out, int out_size, void* d_ws, size_t ws_size,
                              hipStream_t stream) {
  const float* q = (const float*)d_in[0];
  const float* k = (const float*)d_in[1];
  const float* v = (const float*)d_in[2];
  const float* proj = (const float*)d_in[3];
  float* outp = (float*)d_out;

  char* ws = (char*)d_ws;
  unsigned* stabKey = (unsigned*)(ws + oStab);
  float* EsumG = (float*)(ws + oEsum);
  float* VsumG = (float*)(ws + oVsum);
  float* kshatG = (float*)(ws + oKshat);
  float* ctxEG = (float*)(ws + oCtxE);
  short* ctHG = (short*)(ws + oCtH);
  short* PhG = (short*)(ws + oPh);
  short* PlG = (short*)(ws + oPl);

  hipMemsetAsync(d_ws, 0, kZeroBytes, stream);
  perf_prep<<<16, 256, 0, stream>>>(proj, PhG, PlG);
  perf_kside<<<dim3(BHn, 8), 512, 0, stream>>>(k, v, PhG, PlG, stabKey, EsumG, VsumG, ctxEG);
  perf_combine<<<dim3(BHn, 4), 256, 0, stream>>>(stabKey, EsumG, VsumG, ctxEG, kshatG, ctHG);
  perf_qside<<<dim3(BHn, 64), 512, 0, stream>>>(q, PhG, PlG, kshatG, ctHG, outp);
}